// Round 7
// baseline (63.408 us; speedup 1.0000x reference)
//
#include <hip/hip_runtime.h>
#include <math.h>

// ---------------------------------------------------------------------------
// DetectionLoss — exact-semantics anchor loss.
//
// ws layout (bytes):   (reverted to R4 layout)
//   [0    ) int   npos[96]
//   [1024 ) float sum_bce_pos[96]
//   [2048 ) float sum_ce[96]
//   [3072 ) float sum_sl1[96]
//   [4096 ) float tot[3]
//   [4112 ) int   dcount
//   [8192 ) uint  keys[2064384]   order-mapped BCE of negatives (0 = not neg)
//
// Measured floor note: the harness's 256 MiB d_ws poison fill (~39 µs) runs
// inside every timed replay — treat total = 39.2 + our kernels.
// ---------------------------------------------------------------------------

#define BATCH 32
#define NBOX 20

#define KEY_OFS0 0
#define KEY_OFS1 1572864   // 32 * 128*128*3
#define KEY_OFS2 1966080   // + 32 * 64*64*3

__device__ __forceinline__ unsigned mapf(float f) {
    unsigned u = __float_as_uint(f);
    return (u & 0x80000000u) ? ~u : (u | 0x80000000u);
}
__device__ __forceinline__ float unmapf(unsigned k) {
    unsigned u = (k & 0x80000000u) ? (k & 0x7FFFFFFFu) : ~k;
    return __uint_as_float(u);
}

// ---------------------------------------------------------------------------
// Kernel 0: zero the small stats region.
// ---------------------------------------------------------------------------
__global__ __launch_bounds__(1024) void k_init(int* __restrict__ ws)
{
    for (int i = threadIdx.x; i < 1040; i += 1024) ws[i] = 0;
}

// ---------------------------------------------------------------------------
// Kernel 1: per-anchor assignment + BCE + pos-side losses.
// 2 pixels/thread (box LDS reads amortized over both; 6 independent argmax
// chains for ILP). Union uses precomputed C[s][m] = a_s + area_m; the
// fmaxf(uni,1e-8) clamp is dropped (uni >= 144 always; clamp never binds).
// Division-free IoU argmax: rational compare inter*bu > bi*uni.
// ---------------------------------------------------------------------------
__global__ __launch_bounds__(256) void k_assign(
    const float* __restrict__ pred0, const float* __restrict__ pred1,
    const float* __restrict__ pred2,
    const float* __restrict__ tboxes, const int* __restrict__ tlabels,
    int* __restrict__ nposA, float* __restrict__ sumbce,
    float* __restrict__ sumce, float* __restrict__ sumsl1,
    unsigned* __restrict__ keys)
{
    int bid = blockIdx.x;
    int l, rel;
    if (bid < 1024)      { l = 0; rel = bid; }
    else if (bid < 1280) { l = 1; rel = bid - 1024; }
    else                 { l = 2; rel = bid - 1280; }

    int lw, stridei, bpi, keyofs;
    const float* pred;
    if (l == 0)      { lw = 7; stridei = 8;  bpi = 32; pred = pred0; keyofs = KEY_OFS0; }
    else if (l == 1) { lw = 6; stridei = 16; bpi = 8;  pred = pred1; keyofs = KEY_OFS1; }
    else             { lw = 5; stridei = 32; bpi = 2;  pred = pred2; keyofs = KEY_OFS2; }
    int W  = 1 << lw;
    int HW = W * W;
    int b  = rel / bpi;
    int pb = rel - b * bpi;
    int li = l * BATCH + b;
    int t  = threadIdx.x;
    int p0 = pb * 512 + t;       // pixel pair: p0 and p0+256
    int p1 = p0 + 256;

    float fs = (float)stridei;
    float h0 = 0.75f * fs, h1 = 1.125f * fs, h2 = 1.5f * fs;
    float a0 = (2.f*h0)*(2.f*h0), a1 = (2.f*h1)*(2.f*h1), a2 = (2.f*h2)*(2.f*h2);

    __shared__ float sbb[NBOX * 4];
    __shared__ float sC[3 * NBOX];     // C[s][m] = a_s + area_m
    __shared__ int   slab[NBOX];
    if (t < 80) sbb[t] = tboxes[b * 80 + t];
    if (t >= 128 && t < 148) slab[t - 128] = tlabels[b * 20 + (t - 128)];
    __syncthreads();
    if (t < 60) {
        int s = t / 20, m = t - s * 20;
        float area = (sbb[4*m+2] - sbb[4*m]) * (sbb[4*m+3] - sbb[4*m+1]);
        float as = (s == 0) ? a0 : ((s == 1) ? a1 : a2);
        sC[t] = as + area;
    }
    __syncthreads();

    float cxA = ((p0 & (W - 1)) + 0.5f) * fs;
    float cyA = ((p0 >> lw)     + 0.5f) * fs;
    float cxB = ((p1 & (W - 1)) + 0.5f) * fs;
    float cyB = ((p1 >> lw)     + 0.5f) * fs;

    // 6 independent rational argmax chains (2 px x 3 scales)
    float biA0=-1.f,buA0=1.f, biA1=-1.f,buA1=1.f, biA2=-1.f,buA2=1.f;
    float biB0=-1.f,buB0=1.f, biB1=-1.f,buB1=1.f, biB2=-1.f,buB2=1.f;
    int   idA0=0, idA1=0, idA2=0, idB0=0, idB1=0, idB2=0;

    #pragma unroll
    for (int m = 0; m < NBOX; ++m) {
        float bx0 = sbb[4*m], by0 = sbb[4*m+1], bx1 = sbb[4*m+2], by1 = sbb[4*m+3];
        float C0 = sC[m], C1 = sC[20 + m], C2 = sC[40 + m];

        // pixel A
        {
            float dx0 = cxA - bx0, dx1 = bx1 - cxA;
            float dy0 = cyA - by0, dy1 = by1 - cyA;
            {
                float ix = fmaxf(fminf(h0, dx0) + fminf(h0, dx1), 0.f);
                float iy = fmaxf(fminf(h0, dy0) + fminf(h0, dy1), 0.f);
                float inter = ix * iy;
                float uni   = C0 - inter;
                if (inter * buA0 > biA0 * uni) { biA0 = inter; buA0 = uni; idA0 = m; }
            }
            {
                float ix = fmaxf(fminf(h1, dx0) + fminf(h1, dx1), 0.f);
                float iy = fmaxf(fminf(h1, dy0) + fminf(h1, dy1), 0.f);
                float inter = ix * iy;
                float uni   = C1 - inter;
                if (inter * buA1 > biA1 * uni) { biA1 = inter; buA1 = uni; idA1 = m; }
            }
            {
                float ix = fmaxf(fminf(h2, dx0) + fminf(h2, dx1), 0.f);
                float iy = fmaxf(fminf(h2, dy0) + fminf(h2, dy1), 0.f);
                float inter = ix * iy;
                float uni   = C2 - inter;
                if (inter * buA2 > biA2 * uni) { biA2 = inter; buA2 = uni; idA2 = m; }
            }
        }
        // pixel B
        {
            float dx0 = cxB - bx0, dx1 = bx1 - cxB;
            float dy0 = cyB - by0, dy1 = by1 - cyB;
            {
                float ix = fmaxf(fminf(h0, dx0) + fminf(h0, dx1), 0.f);
                float iy = fmaxf(fminf(h0, dy0) + fminf(h0, dy1), 0.f);
                float inter = ix * iy;
                float uni   = C0 - inter;
                if (inter * buB0 > biB0 * uni) { biB0 = inter; buB0 = uni; idB0 = m; }
            }
            {
                float ix = fmaxf(fminf(h1, dx0) + fminf(h1, dx1), 0.f);
                float iy = fmaxf(fminf(h1, dy0) + fminf(h1, dy1), 0.f);
                float inter = ix * iy;
                float uni   = C1 - inter;
                if (inter * buB1 > biB1 * uni) { biB1 = inter; buB1 = uni; idB1 = m; }
            }
            {
                float ix = fmaxf(fminf(h2, dx0) + fminf(h2, dx1), 0.f);
                float iy = fmaxf(fminf(h2, dy0) + fminf(h2, dy1), 0.f);
                float inter = ix * iy;
                float uni   = C2 - inter;
                if (inter * buB2 > biB2 * uni) { biB2 = inter; buB2 = uni; idB2 = m; }
            }
        }
    }

    const float* pbase = pred + (size_t)b * 24 * HW;
    unsigned* kbase = keys + keyofs + (size_t)b * HW * 3;

    auto do_scale = [&](int s, int p, float bi, float bu, int idx) {
        bool pos = bi >= 0.5f * bu;
        bool neg = bi < 0.4f * bu;
        float obj = pbase[(size_t)(s * 8 + 4) * HW + p];
        float sp  = fmaxf(obj, 0.f) + __logf(1.f + __expf(-fabsf(obj)));
        float bce = pos ? sp - obj : sp;
        kbase[s * HW + p] = neg ? mapf(bce) : 0u;   // coalesced per-s plane
        if (pos) {
            atomicAdd(&nposA[li], 1);
            atomicAdd(&sumbce[li], bce);
            float c0 = pbase[(size_t)(s * 8 + 5) * HW + p];
            float c1 = pbase[(size_t)(s * 8 + 6) * HW + p];
            float c2 = pbase[(size_t)(s * 8 + 7) * HW + p];
            float mx = fmaxf(c0, fmaxf(c1, c2));
            float lse = mx + __logf(__expf(c0 - mx) + __expf(c1 - mx) + __expf(c2 - mx));
            int lab = slab[idx] - 1;
            float cl = (lab == 0) ? c0 : ((lab == 1) ? c1 : c2);
            atomicAdd(&sumce[li], lse - cl);
            float ssum = 0.f;
            #pragma unroll
            for (int q = 0; q < 4; ++q) {
                float d  = pbase[(size_t)(s * 8 + q) * HW + p] - sbb[4 * idx + q];
                float ad = fabsf(d);
                ssum += (ad < 1.f) ? 0.5f * d * d : ad - 0.5f;
            }
            atomicAdd(&sumsl1[li], ssum);
        }
    };
    do_scale(0, p0, biA0, buA0, idA0);
    do_scale(1, p0, biA1, buA1, idA1);
    do_scale(2, p0, biA2, buA2, idA2);
    do_scale(0, p1, biB0, buB0, idB0);
    do_scale(1, p1, biB1, buB1, idB1);
    do_scale(2, p1, biB2, buB2, idB2);
}

// ---------------------------------------------------------------------------
// Kernel 2: per-(level,image) exact top-K negative radix select + finalize.
// (R4 version, verbatim — measured ~3-4 us.)
// ---------------------------------------------------------------------------
__global__ __launch_bounds__(1024) void k_select(
    const int* __restrict__ nposA, const float* __restrict__ sumbce,
    const float* __restrict__ sumce, const float* __restrict__ sumsl1,
    const unsigned* __restrict__ keys, float* __restrict__ tot,
    int* __restrict__ dcount, float* __restrict__ out)
{
    int li = blockIdx.x;
    int t  = threadIdx.x;
    int np = nposA[li];

    __shared__ int   lhist[256];
    __shared__ float lsumf[256];
    __shared__ int   sufi[257];
    __shared__ float suff[257];
    __shared__ int   wtot[4];
    __shared__ float wtotf[4];
    __shared__ int   s_bin, s_want, s_K;
    __shared__ float s_extra;
    __shared__ float redbuf[16];

    if (np > 0) {
        int l = li >> 5, b = li & 31;
        int HW, keyofs;
        if (l == 0)      { HW = 16384; keyofs = KEY_OFS0; }
        else if (l == 1) { HW = 4096;  keyofs = KEY_OFS1; }
        else             { HW = 1024;  keyofs = KEY_OFS2; }
        int N  = HW * 3;
        int N4 = N >> 2;
        const uint4* kk4 = reinterpret_cast<const uint4*>(keys + keyofs + (size_t)b * N);

        unsigned prefix = 0;
        int K = 0, want = 0;
        float negsum = 0.f;
        int lane = t & 63;

        for (int pass = 0; pass < 4; ++pass) {
            if (t < 256) { lhist[t] = 0; lsumf[t] = 0.f; }
            __syncthreads();

            float big = 0.f;
            if (pass == 0) {
                for (int i = t; i < N4; i += 1024) {
                    uint4 k4 = kk4[i];
                    atomicAdd(&lhist[k4.x >> 24], 1);
                    atomicAdd(&lhist[k4.y >> 24], 1);
                    atomicAdd(&lhist[k4.z >> 24], 1);
                    atomicAdd(&lhist[k4.w >> 24], 1);
                }
            } else if (pass < 3) {
                int shift = 24 - 8 * pass;
                for (int i = t; i < N4; i += 1024) {
                    uint4 k4 = kk4[i];
                    unsigned kA[4] = {k4.x, k4.y, k4.z, k4.w};
                    #pragma unroll
                    for (int j = 0; j < 4; ++j)
                        if ((kA[j] >> (shift + 8)) == prefix)
                            atomicAdd(&lhist[(kA[j] >> shift) & 255u], 1);
                }
            } else {
                for (int i = t; i < N4; i += 1024) {
                    uint4 k4 = kk4[i];
                    unsigned kA[4] = {k4.x, k4.y, k4.z, k4.w};
                    #pragma unroll
                    for (int j = 0; j < 4; ++j) {
                        unsigned key = kA[j];
                        unsigned top = key >> 8;
                        if (top > prefix) big += unmapf(key);
                        else if (top == prefix) {
                            atomicAdd(&lhist[key & 255u], 1);
                            atomicAdd(&lsumf[key & 255u], unmapf(key));
                        }
                    }
                }
                for (int off = 32; off > 0; off >>= 1) big += __shfl_down(big, off, 64);
                if (lane == 0) redbuf[t >> 6] = big;
            }
            __syncthreads();
            if (pass == 3 && t == 0) {
                float sb = 0.f;
                for (int j = 0; j < 16; ++j) sb += redbuf[j];
                s_extra = sb;
            }

            // suffix scan of lhist (and lsumf on pass 3) using threads 0..255
            int v = 0; float vf = 0.f;
            if (t < 256) {
                v = lhist[t]; vf = lsumf[t];
                for (int off = 1; off < 64; off <<= 1) {
                    int   o  = __shfl_down(v,  off, 64);
                    float of = __shfl_down(vf, off, 64);
                    if (lane + off < 64) { v += o; vf += of; }
                }
                if (lane == 0) { wtot[t >> 6] = v; wtotf[t >> 6] = vf; }
            }
            __syncthreads();
            if (t < 256) {
                int w = t >> 6;
                int add = 0; float addf = 0.f;
                for (int j = w + 1; j < 4; ++j) { add += wtot[j]; addf += wtotf[j]; }
                sufi[t] = v + add;
                suff[t] = vf + addf;
            }
            if (t == 0) { sufi[256] = 0; suff[256] = 0.f; }
            __syncthreads();

            if (pass == 0) {
                if (t == 0) s_K = min(3 * np, sufi[128]);
                __syncthreads();
                K = s_K; want = K;
                if (K == 0) break;
            }
            if (t < 256 && sufi[t] >= want && sufi[t + 1] < want) {
                s_bin  = t;
                s_want = want - sufi[t + 1];
            }
            __syncthreads();
            prefix = (prefix << 8) | (unsigned)s_bin;
            want   = s_want;
            __syncthreads();
        }

        if (t == 0) {
            if (K > 0) {
                int b0 = (int)(prefix & 255u);
                negsum = s_extra + suff[b0 + 1] + (float)want * unmapf(prefix);
            }
            int nsel = np + K;
            float obj_l = (sumbce[li] + negsum) / (float)nsel;
            float cls_l = sumce[li] / (float)np;
            float loc_l = sumsl1[li] / (float)(4 * np);
            atomicAdd(&tot[0], obj_l);
            atomicAdd(&tot[1], cls_l);
            atomicAdd(&tot[2], loc_l);
        }
    }

    // fused finalize: last block to arrive writes the output
    __threadfence();
    if (t == 0) {
        int prev = atomicAdd(dcount, 1);
        if (prev == 95) {
            __threadfence();
            float o  = atomicAdd(&tot[0], 0.f) * (1.f / BATCH);
            float c  = atomicAdd(&tot[1], 0.f) * (1.f / BATCH);
            float lo = atomicAdd(&tot[2], 0.f) * (1.f / BATCH);
            out[0] = o; out[1] = c; out[2] = lo; out[3] = o + c + 2.f * lo;
        }
    }
}

extern "C" void kernel_launch(void* const* d_in, const int* in_sizes, int n_in,
                              void* d_out, int out_size, void* d_ws, size_t ws_size,
                              hipStream_t stream) {
    const float* pred0   = (const float*)d_in[0];
    const float* pred1   = (const float*)d_in[1];
    const float* pred2   = (const float*)d_in[2];
    const float* tboxes  = (const float*)d_in[6];
    const int*   tlabels = (const int*)d_in[7];

    char* ws = (char*)d_ws;
    int*      nposA  = (int*)ws;
    float*    sumbce = (float*)(ws + 1024);
    float*    sumce  = (float*)(ws + 2048);
    float*    sumsl1 = (float*)(ws + 3072);
    float*    tot    = (float*)(ws + 4096);
    int*      dcount = (int*)(ws + 4112);
    unsigned* keys   = (unsigned*)(ws + 8192);

    hipLaunchKernelGGL(k_init, dim3(1), dim3(1024), 0, stream, (int*)ws);
    hipLaunchKernelGGL(k_assign, dim3(1344), dim3(256), 0, stream,
                       pred0, pred1, pred2, tboxes, tlabels,
                       nposA, sumbce, sumce, sumsl1, keys);
    hipLaunchKernelGGL(k_select, dim3(96), dim3(1024), 0, stream,
                       nposA, sumbce, sumce, sumsl1, keys, tot, dcount,
                       (float*)d_out);
}

// Round 8
// 50.337 us; speedup vs baseline: 1.2597x; 1.2597x over previous
//
#include <hip/hip_runtime.h>
#include <math.h>

// ---------------------------------------------------------------------------
// DetectionLoss — exact-semantics anchor loss.
//
// ws layout (bytes):
//   [0    ) int   npos[96]
//   [1024 ) float sum_bce_pos[96]
//   [2048 ) float sum_ce[96]
//   [3072 ) float sum_sl1[96]
//   [4096 ) float tot[3]
//   [4112 ) int   dcount
//   [8192 ) uint  keys[2064384]   order-mapped BCE of negatives (0 = not neg)
//
// Measured floor: harness's 256 MiB d_ws poison fill (~39.5 µs) runs inside
// every timed replay — total = ~39.5 + our kernels. Controllable part only.
// ---------------------------------------------------------------------------

#define BATCH 32
#define NBOX 20

#define KEY_OFS0 0
#define KEY_OFS1 1572864   // 32 * 128*128*3
#define KEY_OFS2 1966080   // + 32 * 64*64*3

__device__ __forceinline__ unsigned mapf(float f) {
    unsigned u = __float_as_uint(f);
    return (u & 0x80000000u) ? ~u : (u | 0x80000000u);
}
__device__ __forceinline__ float unmapf(unsigned k) {
    unsigned u = (k & 0x80000000u) ? (k & 0x7FFFFFFFu) : ~k;
    return __uint_as_float(u);
}

// ---------------------------------------------------------------------------
// Kernel 0: zero the small stats region.
// ---------------------------------------------------------------------------
__global__ __launch_bounds__(1024) void k_init(int* __restrict__ ws)
{
    for (int i = threadIdx.x; i < 1040; i += 1024) ws[i] = 0;
}

// ---------------------------------------------------------------------------
// Kernel 1: per-anchor assignment + BCE + pos-side losses, with EXACT
// block-level box pruning: a 256-thread block covers whole rows (256/W =
// 2/4/8), so only boxes whose y-extent intersects the block's row window
// (± hmax) can have IoU > 0 here. Zero-IoU boxes can't win the argmax
// (bi init 0, id init 0 reproduces argmax-of-all-zeros = 0; compaction
// preserves index order for first-max tie-break). ~4/20 boxes survive at
// level 0 => ~4x fewer IoU-loop VALU ops.
// Division-free IoU argmax: rational compare inter*bu > bi*uni.
// ---------------------------------------------------------------------------
__global__ __launch_bounds__(256) void k_assign(
    const float* __restrict__ pred0, const float* __restrict__ pred1,
    const float* __restrict__ pred2,
    const float* __restrict__ tboxes, const int* __restrict__ tlabels,
    int* __restrict__ nposA, float* __restrict__ sumbce,
    float* __restrict__ sumce, float* __restrict__ sumsl1,
    unsigned* __restrict__ keys)
{
    int bid = blockIdx.x;
    int l, rel;
    if (bid < 2048)      { l = 0; rel = bid; }
    else if (bid < 2560) { l = 1; rel = bid - 2048; }
    else                 { l = 2; rel = bid - 2560; }

    int lw, stridei, bpi, keyofs;
    const float* pred;
    if (l == 0)      { lw = 7; stridei = 8;  bpi = 64; pred = pred0; keyofs = KEY_OFS0; }
    else if (l == 1) { lw = 6; stridei = 16; bpi = 16; pred = pred1; keyofs = KEY_OFS1; }
    else             { lw = 5; stridei = 32; bpi = 4;  pred = pred2; keyofs = KEY_OFS2; }
    int W  = 1 << lw;
    int HW = W * W;
    int b  = rel / bpi;
    int pb = rel - b * bpi;
    int li = l * BATCH + b;
    int t  = threadIdx.x;
    int p  = pb * 256 + t;

    float fs = (float)stridei;
    float h0 = 0.75f * fs, h1 = 1.125f * fs, h2 = 1.5f * fs;
    float a0 = (2.f*h0)*(2.f*h0), a1 = (2.f*h1)*(2.f*h1), a2 = (2.f*h2)*(2.f*h2);

    __shared__ float sbb[NBOX * 4];          // all boxes (pos path needs them)
    __shared__ int   slab[NBOX];
    __shared__ float scb[NBOX * 4];          // compacted survivor boxes
    __shared__ float sc0[NBOX], sc1[NBOX], sc2[NBOX];   // C[s] = a_s + area
    __shared__ int   sidx[NBOX];             // survivor -> original index
    __shared__ int   s_nact;

    if (t < 80) sbb[t] = tboxes[b * 80 + t];
    if (t >= 128 && t < 148) slab[t - 128] = tlabels[b * 20 + (t - 128)];
    __syncthreads();

    // block row window (block-uniform): rows r0..r1, anchors reach +-h2
    {
        int rows = 256 >> lw;
        int r0   = (pb * 256) >> lw;
        float ymin = (r0 + 0.5f) * fs - h2;
        float ymax = (r0 + rows - 1 + 0.5f) * fs + h2;
        if (t < 64) {   // wave 0 does ballot-compaction
            bool act = false;
            float bx0=0.f, by0=0.f, bx1=0.f, by1=0.f;
            if (t < NBOX) {
                bx0 = sbb[4*t]; by0 = sbb[4*t+1]; bx1 = sbb[4*t+2]; by1 = sbb[4*t+3];
                act = (by1 > ymin) && (by0 < ymax);
            }
            unsigned long long mask = __ballot(act);
            if (act) {
                int k = (int)__popcll(mask & ((1ull << t) - 1ull));
                scb[4*k] = bx0; scb[4*k+1] = by0; scb[4*k+2] = bx1; scb[4*k+3] = by1;
                float area = (bx1 - bx0) * (by1 - by0);
                sc0[k] = a0 + area; sc1[k] = a1 + area; sc2[k] = a2 + area;
                sidx[k] = t;
            }
            if (t == 0) s_nact = (int)__popcll(mask);
        }
    }
    __syncthreads();
    int nact = s_nact;

    float cx = ((p & (W - 1)) + 0.5f) * fs;
    float cy = ((p >> lw)     + 0.5f) * fs;

    // rational best: bi/bu, init 0/1 with id 0 (== argmax when all IoU = 0)
    float bi0 = 0.f, bu0 = 1.f, bi1 = 0.f, bu1 = 1.f, bi2 = 0.f, bu2 = 1.f;
    int   id0 = 0, id1 = 0, id2 = 0;

    for (int k = 0; k < nact; ++k) {
        float bx0 = scb[4*k], by0 = scb[4*k+1], bx1 = scb[4*k+2], by1 = scb[4*k+3];
        float C0 = sc0[k], C1 = sc1[k], C2 = sc2[k];
        int   m  = sidx[k];
        float dx0 = cx - bx0, dx1 = bx1 - cx;
        float dy0 = cy - by0, dy1 = by1 - cy;
        {
            float ix = fmaxf(fminf(h0, dx0) + fminf(h0, dx1), 0.f);
            float iy = fmaxf(fminf(h0, dy0) + fminf(h0, dy1), 0.f);
            float inter = ix * iy;
            float uni   = C0 - inter;
            if (inter * bu0 > bi0 * uni) { bi0 = inter; bu0 = uni; id0 = m; }
        }
        {
            float ix = fmaxf(fminf(h1, dx0) + fminf(h1, dx1), 0.f);
            float iy = fmaxf(fminf(h1, dy0) + fminf(h1, dy1), 0.f);
            float inter = ix * iy;
            float uni   = C1 - inter;
            if (inter * bu1 > bi1 * uni) { bi1 = inter; bu1 = uni; id1 = m; }
        }
        {
            float ix = fmaxf(fminf(h2, dx0) + fminf(h2, dx1), 0.f);
            float iy = fmaxf(fminf(h2, dy0) + fminf(h2, dy1), 0.f);
            float inter = ix * iy;
            float uni   = C2 - inter;
            if (inter * bu2 > bi2 * uni) { bi2 = inter; bu2 = uni; id2 = m; }
        }
    }

    const float* pbase = pred + (size_t)b * 24 * HW;
    unsigned* kbase = keys + keyofs + (size_t)b * HW * 3;

    auto do_scale = [&](int s, float bi, float bu, int idx) {
        bool pos = bi >= 0.5f * bu;
        bool neg = bi < 0.4f * bu;
        float obj = pbase[(size_t)(s * 8 + 4) * HW + p];
        float sp  = fmaxf(obj, 0.f) + __logf(1.f + __expf(-fabsf(obj)));
        float bce = pos ? sp - obj : sp;
        kbase[s * HW + p] = neg ? mapf(bce) : 0u;   // coalesced per-s plane
        if (pos) {
            atomicAdd(&nposA[li], 1);
            atomicAdd(&sumbce[li], bce);
            float c0 = pbase[(size_t)(s * 8 + 5) * HW + p];
            float c1 = pbase[(size_t)(s * 8 + 6) * HW + p];
            float c2 = pbase[(size_t)(s * 8 + 7) * HW + p];
            float mx = fmaxf(c0, fmaxf(c1, c2));
            float lse = mx + __logf(__expf(c0 - mx) + __expf(c1 - mx) + __expf(c2 - mx));
            int lab = slab[idx] - 1;
            float cl = (lab == 0) ? c0 : ((lab == 1) ? c1 : c2);
            atomicAdd(&sumce[li], lse - cl);
            float ssum = 0.f;
            #pragma unroll
            for (int q = 0; q < 4; ++q) {
                float d  = pbase[(size_t)(s * 8 + q) * HW + p] - sbb[4 * idx + q];
                float ad = fabsf(d);
                ssum += (ad < 1.f) ? 0.5f * d * d : ad - 0.5f;
            }
            atomicAdd(&sumsl1[li], ssum);
        }
    };
    do_scale(0, bi0, bu0, id0);
    do_scale(1, bi1, bu1, id1);
    do_scale(2, bi2, bu2, id2);
}

// ---------------------------------------------------------------------------
// Kernel 2: per-(level,image) exact top-K negative radix select + finalize.
// (R4 version, verbatim — measured ~3-4 us.)
// ---------------------------------------------------------------------------
__global__ __launch_bounds__(1024) void k_select(
    const int* __restrict__ nposA, const float* __restrict__ sumbce,
    const float* __restrict__ sumce, const float* __restrict__ sumsl1,
    const unsigned* __restrict__ keys, float* __restrict__ tot,
    int* __restrict__ dcount, float* __restrict__ out)
{
    int li = blockIdx.x;
    int t  = threadIdx.x;
    int np = nposA[li];

    __shared__ int   lhist[256];
    __shared__ float lsumf[256];
    __shared__ int   sufi[257];
    __shared__ float suff[257];
    __shared__ int   wtot[4];
    __shared__ float wtotf[4];
    __shared__ int   s_bin, s_want, s_K;
    __shared__ float s_extra;
    __shared__ float redbuf[16];

    if (np > 0) {
        int l = li >> 5, b = li & 31;
        int HW, keyofs;
        if (l == 0)      { HW = 16384; keyofs = KEY_OFS0; }
        else if (l == 1) { HW = 4096;  keyofs = KEY_OFS1; }
        else             { HW = 1024;  keyofs = KEY_OFS2; }
        int N  = HW * 3;
        int N4 = N >> 2;
        const uint4* kk4 = reinterpret_cast<const uint4*>(keys + keyofs + (size_t)b * N);

        unsigned prefix = 0;
        int K = 0, want = 0;
        float negsum = 0.f;
        int lane = t & 63;

        for (int pass = 0; pass < 4; ++pass) {
            if (t < 256) { lhist[t] = 0; lsumf[t] = 0.f; }
            __syncthreads();

            float big = 0.f;
            if (pass == 0) {
                for (int i = t; i < N4; i += 1024) {
                    uint4 k4 = kk4[i];
                    atomicAdd(&lhist[k4.x >> 24], 1);
                    atomicAdd(&lhist[k4.y >> 24], 1);
                    atomicAdd(&lhist[k4.z >> 24], 1);
                    atomicAdd(&lhist[k4.w >> 24], 1);
                }
            } else if (pass < 3) {
                int shift = 24 - 8 * pass;
                for (int i = t; i < N4; i += 1024) {
                    uint4 k4 = kk4[i];
                    unsigned kA[4] = {k4.x, k4.y, k4.z, k4.w};
                    #pragma unroll
                    for (int j = 0; j < 4; ++j)
                        if ((kA[j] >> (shift + 8)) == prefix)
                            atomicAdd(&lhist[(kA[j] >> shift) & 255u], 1);
                }
            } else {
                for (int i = t; i < N4; i += 1024) {
                    uint4 k4 = kk4[i];
                    unsigned kA[4] = {k4.x, k4.y, k4.z, k4.w};
                    #pragma unroll
                    for (int j = 0; j < 4; ++j) {
                        unsigned key = kA[j];
                        unsigned top = key >> 8;
                        if (top > prefix) big += unmapf(key);
                        else if (top == prefix) {
                            atomicAdd(&lhist[key & 255u], 1);
                            atomicAdd(&lsumf[key & 255u], unmapf(key));
                        }
                    }
                }
                for (int off = 32; off > 0; off >>= 1) big += __shfl_down(big, off, 64);
                if (lane == 0) redbuf[t >> 6] = big;
            }
            __syncthreads();
            if (pass == 3 && t == 0) {
                float sb = 0.f;
                for (int j = 0; j < 16; ++j) sb += redbuf[j];
                s_extra = sb;
            }

            // suffix scan of lhist (and lsumf on pass 3) using threads 0..255
            int v = 0; float vf = 0.f;
            if (t < 256) {
                v = lhist[t]; vf = lsumf[t];
                for (int off = 1; off < 64; off <<= 1) {
                    int   o  = __shfl_down(v,  off, 64);
                    float of = __shfl_down(vf, off, 64);
                    if (lane + off < 64) { v += o; vf += of; }
                }
                if (lane == 0) { wtot[t >> 6] = v; wtotf[t >> 6] = vf; }
            }
            __syncthreads();
            if (t < 256) {
                int w = t >> 6;
                int add = 0; float addf = 0.f;
                for (int j = w + 1; j < 4; ++j) { add += wtot[j]; addf += wtotf[j]; }
                sufi[t] = v + add;
                suff[t] = vf + addf;
            }
            if (t == 0) { sufi[256] = 0; suff[256] = 0.f; }
            __syncthreads();

            if (pass == 0) {
                if (t == 0) s_K = min(3 * np, sufi[128]);
                __syncthreads();
                K = s_K; want = K;
                if (K == 0) break;
            }
            if (t < 256 && sufi[t] >= want && sufi[t + 1] < want) {
                s_bin  = t;
                s_want = want - sufi[t + 1];
            }
            __syncthreads();
            prefix = (prefix << 8) | (unsigned)s_bin;
            want   = s_want;
            __syncthreads();
        }

        if (t == 0) {
            if (K > 0) {
                int b0 = (int)(prefix & 255u);
                negsum = s_extra + suff[b0 + 1] + (float)want * unmapf(prefix);
            }
            int nsel = np + K;
            float obj_l = (sumbce[li] + negsum) / (float)nsel;
            float cls_l = sumce[li] / (float)np;
            float loc_l = sumsl1[li] / (float)(4 * np);
            atomicAdd(&tot[0], obj_l);
            atomicAdd(&tot[1], cls_l);
            atomicAdd(&tot[2], loc_l);
        }
    }

    // fused finalize: last block to arrive writes the output
    __threadfence();
    if (t == 0) {
        int prev = atomicAdd(dcount, 1);
        if (prev == 95) {
            __threadfence();
            float o  = atomicAdd(&tot[0], 0.f) * (1.f / BATCH);
            float c  = atomicAdd(&tot[1], 0.f) * (1.f / BATCH);
            float lo = atomicAdd(&tot[2], 0.f) * (1.f / BATCH);
            out[0] = o; out[1] = c; out[2] = lo; out[3] = o + c + 2.f * lo;
        }
    }
}

extern "C" void kernel_launch(void* const* d_in, const int* in_sizes, int n_in,
                              void* d_out, int out_size, void* d_ws, size_t ws_size,
                              hipStream_t stream) {
    const float* pred0   = (const float*)d_in[0];
    const float* pred1   = (const float*)d_in[1];
    const float* pred2   = (const float*)d_in[2];
    const float* tboxes  = (const float*)d_in[6];
    const int*   tlabels = (const int*)d_in[7];

    char* ws = (char*)d_ws;
    int*      nposA  = (int*)ws;
    float*    sumbce = (float*)(ws + 1024);
    float*    sumce  = (float*)(ws + 2048);
    float*    sumsl1 = (float*)(ws + 3072);
    float*    tot    = (float*)(ws + 4096);
    int*      dcount = (int*)(ws + 4112);
    unsigned* keys   = (unsigned*)(ws + 8192);

    hipLaunchKernelGGL(k_init, dim3(1), dim3(1024), 0, stream, (int*)ws);
    hipLaunchKernelGGL(k_assign, dim3(2688), dim3(256), 0, stream,
                       pred0, pred1, pred2, tboxes, tlabels,
                       nposA, sumbce, sumce, sumsl1, keys);
    hipLaunchKernelGGL(k_select, dim3(96), dim3(1024), 0, stream,
                       nposA, sumbce, sumce, sumsl1, keys, tot, dcount,
                       (float*)d_out);
}

// Round 9
// 33.271 us; speedup vs baseline: 1.9058x; 1.5129x over previous
//
#include <hip/hip_runtime.h>
#include <math.h>

// ---------------------------------------------------------------------------
// DetectionLoss — exact-semantics anchor loss. 2 dispatches, zero-init-free.
//
// ws layout (bytes):
//   [8192  ) float4 pstats[2688]   per-assign-block {npos, bce, ce, sl1}
//   [65536 ) uint   keys[2064384]  order-mapped BCE of negatives (0 = not neg)
//
// pstats is written unconditionally by every k_assign block -> no init pass.
// d_out is zeroed by k_assign (stream-ordered before k_select's atomics).
//
// Measured floor: harness's 256 MiB d_ws poison fill (~39.5 µs) runs inside
// every timed replay — total = ~39.5 + our kernels.
// ---------------------------------------------------------------------------

#define BATCH 32
#define NBOX 20

#define KEY_OFS0 0
#define KEY_OFS1 1572864   // 32 * 128*128*3
#define KEY_OFS2 1966080   // + 32 * 64*64*3

__device__ __forceinline__ unsigned mapf(float f) {
    unsigned u = __float_as_uint(f);
    return (u & 0x80000000u) ? ~u : (u | 0x80000000u);
}
__device__ __forceinline__ float unmapf(unsigned k) {
    unsigned u = (k & 0x80000000u) ? (k & 0x7FFFFFFFu) : ~k;
    return __uint_as_float(u);
}

// ---------------------------------------------------------------------------
// Kernel 1: per-anchor assignment + BCE + pos-side losses, with EXACT
// block-level box pruning (R8, verified): only boxes whose y-extent
// intersects the block's row window (± hmax) can have IoU > 0 here.
// Stats leave via a per-block reduction -> pstats[bid] (no atomics, no init).
// ---------------------------------------------------------------------------
__global__ __launch_bounds__(256) void k_assign(
    const float* __restrict__ pred0, const float* __restrict__ pred1,
    const float* __restrict__ pred2,
    const float* __restrict__ tboxes, const int* __restrict__ tlabels,
    float4* __restrict__ pstats, unsigned* __restrict__ keys,
    float* __restrict__ out)
{
    int bid = blockIdx.x;
    int t  = threadIdx.x;
    if (bid == 0 && t == 0) {     // zero output accumulators for this replay
        out[0] = 0.f; out[1] = 0.f; out[2] = 0.f; out[3] = 0.f;
    }

    int l, rel;
    if (bid < 2048)      { l = 0; rel = bid; }
    else if (bid < 2560) { l = 1; rel = bid - 2048; }
    else                 { l = 2; rel = bid - 2560; }

    int lw, stridei, bpi, keyofs;
    const float* pred;
    if (l == 0)      { lw = 7; stridei = 8;  bpi = 64; pred = pred0; keyofs = KEY_OFS0; }
    else if (l == 1) { lw = 6; stridei = 16; bpi = 16; pred = pred1; keyofs = KEY_OFS1; }
    else             { lw = 5; stridei = 32; bpi = 4;  pred = pred2; keyofs = KEY_OFS2; }
    int W  = 1 << lw;
    int HW = W * W;
    int b  = rel / bpi;
    int pb = rel - b * bpi;
    int p  = pb * 256 + t;

    float fs = (float)stridei;
    float h0 = 0.75f * fs, h1 = 1.125f * fs, h2 = 1.5f * fs;
    float a0 = (2.f*h0)*(2.f*h0), a1 = (2.f*h1)*(2.f*h1), a2 = (2.f*h2)*(2.f*h2);

    __shared__ float sbb[NBOX * 4];          // all boxes (pos path needs them)
    __shared__ int   slab[NBOX];
    __shared__ float scb[NBOX * 4];          // compacted survivor boxes
    __shared__ float sc0[NBOX], sc1[NBOX], sc2[NBOX];   // C[s] = a_s + area
    __shared__ int   sidx[NBOX];             // survivor -> original index
    __shared__ int   s_nact;

    if (t < 80) sbb[t] = tboxes[b * 80 + t];
    if (t >= 128 && t < 148) slab[t - 128] = tlabels[b * 20 + (t - 128)];
    __syncthreads();

    // block row window (block-uniform): rows r0..r0+rows-1, anchors reach ±h2
    {
        int rows = 256 >> lw;
        int r0   = (pb * 256) >> lw;
        float ymin = (r0 + 0.5f) * fs - h2;
        float ymax = (r0 + rows - 1 + 0.5f) * fs + h2;
        if (t < 64) {   // wave 0 does ballot-compaction
            bool act = false;
            float bx0=0.f, by0=0.f, bx1=0.f, by1=0.f;
            if (t < NBOX) {
                bx0 = sbb[4*t]; by0 = sbb[4*t+1]; bx1 = sbb[4*t+2]; by1 = sbb[4*t+3];
                act = (by1 > ymin) && (by0 < ymax);
            }
            unsigned long long mask = __ballot(act);
            if (act) {
                int k = (int)__popcll(mask & ((1ull << t) - 1ull));
                scb[4*k] = bx0; scb[4*k+1] = by0; scb[4*k+2] = bx1; scb[4*k+3] = by1;
                float area = (bx1 - bx0) * (by1 - by0);
                sc0[k] = a0 + area; sc1[k] = a1 + area; sc2[k] = a2 + area;
                sidx[k] = t;
            }
            if (t == 0) s_nact = (int)__popcll(mask);
        }
    }
    __syncthreads();
    int nact = s_nact;

    float cx = ((p & (W - 1)) + 0.5f) * fs;
    float cy = ((p >> lw)     + 0.5f) * fs;

    // rational best: bi/bu, init 0/1 with id 0 (== argmax when all IoU = 0)
    float bi0 = 0.f, bu0 = 1.f, bi1 = 0.f, bu1 = 1.f, bi2 = 0.f, bu2 = 1.f;
    int   id0 = 0, id1 = 0, id2 = 0;

    for (int k = 0; k < nact; ++k) {
        float bx0 = scb[4*k], by0 = scb[4*k+1], bx1 = scb[4*k+2], by1 = scb[4*k+3];
        float C0 = sc0[k], C1 = sc1[k], C2 = sc2[k];
        int   m  = sidx[k];
        float dx0 = cx - bx0, dx1 = bx1 - cx;
        float dy0 = cy - by0, dy1 = by1 - cy;
        {
            float ix = fmaxf(fminf(h0, dx0) + fminf(h0, dx1), 0.f);
            float iy = fmaxf(fminf(h0, dy0) + fminf(h0, dy1), 0.f);
            float inter = ix * iy;
            float uni   = C0 - inter;
            if (inter * bu0 > bi0 * uni) { bi0 = inter; bu0 = uni; id0 = m; }
        }
        {
            float ix = fmaxf(fminf(h1, dx0) + fminf(h1, dx1), 0.f);
            float iy = fmaxf(fminf(h1, dy0) + fminf(h1, dy1), 0.f);
            float inter = ix * iy;
            float uni   = C1 - inter;
            if (inter * bu1 > bi1 * uni) { bi1 = inter; bu1 = uni; id1 = m; }
        }
        {
            float ix = fmaxf(fminf(h2, dx0) + fminf(h2, dx1), 0.f);
            float iy = fmaxf(fminf(h2, dy0) + fminf(h2, dy1), 0.f);
            float inter = ix * iy;
            float uni   = C2 - inter;
            if (inter * bu2 > bi2 * uni) { bi2 = inter; bu2 = uni; id2 = m; }
        }
    }

    const float* pbase = pred + (size_t)b * 24 * HW;
    unsigned* kbase = keys + keyofs + (size_t)b * HW * 3;

    float my_np = 0.f, my_bce = 0.f, my_ce = 0.f, my_sl1 = 0.f;

    auto do_scale = [&](int s, float bi, float bu, int idx) {
        bool pos = bi >= 0.5f * bu;
        bool neg = bi < 0.4f * bu;
        float obj = pbase[(size_t)(s * 8 + 4) * HW + p];
        float sp  = fmaxf(obj, 0.f) + __logf(1.f + __expf(-fabsf(obj)));
        float bce = pos ? sp - obj : sp;
        kbase[s * HW + p] = neg ? mapf(bce) : 0u;   // coalesced per-s plane
        if (pos) {
            my_np += 1.f;
            my_bce += bce;
            float c0 = pbase[(size_t)(s * 8 + 5) * HW + p];
            float c1 = pbase[(size_t)(s * 8 + 6) * HW + p];
            float c2 = pbase[(size_t)(s * 8 + 7) * HW + p];
            float mx = fmaxf(c0, fmaxf(c1, c2));
            float lse = mx + __logf(__expf(c0 - mx) + __expf(c1 - mx) + __expf(c2 - mx));
            int lab = slab[idx] - 1;
            float cl = (lab == 0) ? c0 : ((lab == 1) ? c1 : c2);
            my_ce += lse - cl;
            float ssum = 0.f;
            #pragma unroll
            for (int q = 0; q < 4; ++q) {
                float d  = pbase[(size_t)(s * 8 + q) * HW + p] - sbb[4 * idx + q];
                float ad = fabsf(d);
                ssum += (ad < 1.f) ? 0.5f * d * d : ad - 0.5f;
            }
            my_sl1 += ssum;
        }
    };
    do_scale(0, bi0, bu0, id0);
    do_scale(1, bi1, bu1, id1);
    do_scale(2, bi2, bu2, id2);

    // per-block reduction -> pstats[bid] (written unconditionally, no init)
    #pragma unroll
    for (int off = 32; off > 0; off >>= 1) {
        my_np  += __shfl_down(my_np,  off, 64);
        my_bce += __shfl_down(my_bce, off, 64);
        my_ce  += __shfl_down(my_ce,  off, 64);
        my_sl1 += __shfl_down(my_sl1, off, 64);
    }
    __shared__ float red[4][4];
    int lane = t & 63, w = t >> 6;
    if (lane == 0) { red[w][0] = my_np; red[w][1] = my_bce; red[w][2] = my_ce; red[w][3] = my_sl1; }
    __syncthreads();
    if (t == 0) {
        float4 o;
        o.x = red[0][0] + red[1][0] + red[2][0] + red[3][0];
        o.y = red[0][1] + red[1][1] + red[2][1] + red[3][1];
        o.z = red[0][2] + red[1][2] + red[2][2] + red[3][2];
        o.w = red[0][3] + red[1][3] + red[2][3] + red[3][3];
        pstats[bid] = o;
    }
}

// ---------------------------------------------------------------------------
// Kernel 2: per-(level,image) stat gather + exact top-K radix select,
// results atomically accumulated into d_out (all 4 components are linear
// in the per-(level,image) losses -> no finalizer kernel needed).
// ---------------------------------------------------------------------------
__global__ __launch_bounds__(1024) void k_select(
    const float4* __restrict__ pstats, const unsigned* __restrict__ keys,
    float* __restrict__ out)
{
    int li = blockIdx.x;
    int t  = threadIdx.x;
    int lane = t & 63;

    __shared__ int   lhist[256];
    __shared__ float lsumf[256];
    __shared__ int   sufi[257];
    __shared__ float suff[257];
    __shared__ int   wtot[4];
    __shared__ float wtotf[4];
    __shared__ int   s_bin, s_want, s_K;
    __shared__ float s_extra;
    __shared__ float redbuf[16];
    __shared__ int   s_np;
    __shared__ float s_bce, s_ce, s_sl1;

    int l = li >> 5, b = li & 31;
    int HW, keyofs, base, nb;
    if (l == 0)      { HW = 16384; keyofs = KEY_OFS0; base = b * 64;        nb = 64; }
    else if (l == 1) { HW = 4096;  keyofs = KEY_OFS1; base = 2048 + b * 16; nb = 16; }
    else             { HW = 1024;  keyofs = KEY_OFS2; base = 2560 + b * 4;  nb = 4;  }

    // gather per-block partials for this (level,image)
    if (t < 64) {
        float4 v = make_float4(0.f, 0.f, 0.f, 0.f);
        if (t < nb) v = pstats[base + t];
        #pragma unroll
        for (int off = 32; off > 0; off >>= 1) {
            v.x += __shfl_down(v.x, off, 64);
            v.y += __shfl_down(v.y, off, 64);
            v.z += __shfl_down(v.z, off, 64);
            v.w += __shfl_down(v.w, off, 64);
        }
        if (t == 0) { s_np = (int)v.x; s_bce = v.y; s_ce = v.z; s_sl1 = v.w; }
    }
    __syncthreads();
    int np = s_np;

    if (np > 0) {
        int N  = HW * 3;
        int N4 = N >> 2;
        const uint4* kk4 = reinterpret_cast<const uint4*>(keys + keyofs + (size_t)b * N);

        unsigned prefix = 0;
        int K = 0, want = 0;
        float negsum = 0.f;

        for (int pass = 0; pass < 4; ++pass) {
            if (t < 256) { lhist[t] = 0; lsumf[t] = 0.f; }
            __syncthreads();

            float big = 0.f;
            if (pass == 0) {
                for (int i = t; i < N4; i += 1024) {
                    uint4 k4 = kk4[i];
                    atomicAdd(&lhist[k4.x >> 24], 1);
                    atomicAdd(&lhist[k4.y >> 24], 1);
                    atomicAdd(&lhist[k4.z >> 24], 1);
                    atomicAdd(&lhist[k4.w >> 24], 1);
                }
            } else if (pass < 3) {
                int shift = 24 - 8 * pass;
                for (int i = t; i < N4; i += 1024) {
                    uint4 k4 = kk4[i];
                    unsigned kA[4] = {k4.x, k4.y, k4.z, k4.w};
                    #pragma unroll
                    for (int j = 0; j < 4; ++j)
                        if ((kA[j] >> (shift + 8)) == prefix)
                            atomicAdd(&lhist[(kA[j] >> shift) & 255u], 1);
                }
            } else {
                for (int i = t; i < N4; i += 1024) {
                    uint4 k4 = kk4[i];
                    unsigned kA[4] = {k4.x, k4.y, k4.z, k4.w};
                    #pragma unroll
                    for (int j = 0; j < 4; ++j) {
                        unsigned key = kA[j];
                        unsigned top = key >> 8;
                        if (top > prefix) big += unmapf(key);
                        else if (top == prefix) {
                            atomicAdd(&lhist[key & 255u], 1);
                            atomicAdd(&lsumf[key & 255u], unmapf(key));
                        }
                    }
                }
                for (int off = 32; off > 0; off >>= 1) big += __shfl_down(big, off, 64);
                if (lane == 0) redbuf[t >> 6] = big;
            }
            __syncthreads();
            if (pass == 3 && t == 0) {
                float sb = 0.f;
                for (int j = 0; j < 16; ++j) sb += redbuf[j];
                s_extra = sb;
            }

            // suffix scan of lhist (and lsumf on pass 3) using threads 0..255
            int v = 0; float vf = 0.f;
            if (t < 256) {
                v = lhist[t]; vf = lsumf[t];
                for (int off = 1; off < 64; off <<= 1) {
                    int   o  = __shfl_down(v,  off, 64);
                    float of = __shfl_down(vf, off, 64);
                    if (lane + off < 64) { v += o; vf += of; }
                }
                if (lane == 0) { wtot[t >> 6] = v; wtotf[t >> 6] = vf; }
            }
            __syncthreads();
            if (t < 256) {
                int w = t >> 6;
                int add = 0; float addf = 0.f;
                for (int j = w + 1; j < 4; ++j) { add += wtot[j]; addf += wtotf[j]; }
                sufi[t] = v + add;
                suff[t] = vf + addf;
            }
            if (t == 0) { sufi[256] = 0; suff[256] = 0.f; }
            __syncthreads();

            if (pass == 0) {
                if (t == 0) s_K = min(3 * np, sufi[128]);
                __syncthreads();
                K = s_K; want = K;
                if (K == 0) break;
            }
            if (t < 256 && sufi[t] >= want && sufi[t + 1] < want) {
                s_bin  = t;
                s_want = want - sufi[t + 1];
            }
            __syncthreads();
            prefix = (prefix << 8) | (unsigned)s_bin;
            want   = s_want;
            __syncthreads();
        }

        if (t == 0) {
            if (K > 0) {
                int b0 = (int)(prefix & 255u);
                negsum = s_extra + suff[b0 + 1] + (float)want * unmapf(prefix);
            }
            int nsel = np + K;
            float obj_l = (s_bce + negsum) / (float)nsel;
            float cls_l = s_ce / (float)np;
            float loc_l = s_sl1 / (float)(4 * np);
            const float inv = 1.f / (float)BATCH;
            atomicAdd(&out[0], obj_l * inv);
            atomicAdd(&out[1], cls_l * inv);
            atomicAdd(&out[2], loc_l * inv);
            atomicAdd(&out[3], (obj_l + cls_l + 2.f * loc_l) * inv);
        }
    }
}

extern "C" void kernel_launch(void* const* d_in, const int* in_sizes, int n_in,
                              void* d_out, int out_size, void* d_ws, size_t ws_size,
                              hipStream_t stream) {
    const float* pred0   = (const float*)d_in[0];
    const float* pred1   = (const float*)d_in[1];
    const float* pred2   = (const float*)d_in[2];
    const float* tboxes  = (const float*)d_in[6];
    const int*   tlabels = (const int*)d_in[7];

    char* ws = (char*)d_ws;
    float4*   pstats = (float4*)(ws + 8192);
    unsigned* keys   = (unsigned*)(ws + 65536);

    hipLaunchKernelGGL(k_assign, dim3(2688), dim3(256), 0, stream,
                       pred0, pred1, pred2, tboxes, tlabels,
                       pstats, keys, (float*)d_out);
    hipLaunchKernelGGL(k_select, dim3(96), dim3(1024), 0, stream,
                       pstats, keys, (float*)d_out);
}